// Round 7
// baseline (165.493 us; speedup 1.0000x reference)
//
#include <hip/hip_runtime.h>
#include <hip/hip_bf16.h>
#include <math.h>

#define B_ 8
#define T_ 2048
#define C_ 1024
#define H_ 64

typedef __attribute__((ext_vector_type(8))) __bf16 bf16x8;
typedef __attribute__((ext_vector_type(4))) float f32x4;

static __device__ inline unsigned short f2bf_u(float f) {
    __bf16 b = (__bf16)f;
    return __builtin_bit_cast(unsigned short, b);
}
static __device__ inline unsigned int pack2(float lo, float hi) {
    return (unsigned int)f2bf_u(lo) | ((unsigned int)f2bf_u(hi) << 16);
}
static __device__ inline bf16x8 cvt8(float4 a, float4 b) {
    bf16x8 w;
    w[0] = (__bf16)a.x; w[1] = (__bf16)a.y; w[2] = (__bf16)a.z; w[3] = (__bf16)a.w;
    w[4] = (__bf16)b.x; w[5] = (__bf16)b.y; w[6] = (__bf16)b.z; w[7] = (__bf16)b.w;
    return w;
}

// ---- pack Wq|Wk|Wv fp32 [1024][64] -> Wp bf16 [kt][n][32], n in [0,192) ----
__global__ void prep_w_kernel(const float* __restrict__ Wq,
                              const float* __restrict__ Wk,
                              const float* __restrict__ Wv,
                              unsigned short* __restrict__ Wp) {
    int idx = blockIdx.x * 256 + threadIdx.x;
    if (idx >= C_ * 192) return;
    int k = idx / 192;
    int n = idx % 192;
    const float* W = (n < 64) ? Wq : (n < 128) ? Wk : Wv;
    float val = W[k * 64 + (n & 63)];
    Wp[((size_t)(k >> 5) * 192 + n) * 32 + (k & 31)] = f2bf_u(val);
}

// ---- proj v5: block = 16 rows x 192 cols, x read once.
// ROOT-CAUSE FIX (R6 post-mortem): VGPR_Count=36 proved the compiler
// serialized all register prefetch -> MLP~3 -> 1 TB/s. Stage x as FP32 via
// global_load_lds (async DMA, no VGPRs, can't be serialized), triple-buffered
// 8-kt phases, loads for p+2 issued at top of p. bf16 convert at compute time.
// Row stride 1040 B: DMA needs raw 1 KB rows (base+lane*16); +16 pad makes
// b128 compute reads bank-uniform (stride 260 dw % 32 = 4).
#define XROWB 1040
__global__ __launch_bounds__(256, 3) void proj_kernel(
        const float* __restrict__ x, const unsigned short* __restrict__ Wp,
        unsigned short* __restrict__ q, unsigned short* __restrict__ k,
        unsigned short* __restrict__ vT) {
    __shared__ __align__(16) char xraw[3][16][XROWB];   // 48.75 KB
    const int wave = threadIdx.x >> 6;
    const int lane = threadIdx.x & 63;
    const int col  = lane & 15;
    const int quad = lane >> 4;
    const int row0 = blockIdx.x * 16;
    const int n0   = wave * 48;

    // stage phase p (floats [p*256,(p+1)*256) of each of the 16 rows) into buf.
    // wave w stages rows 4w..4w+3; one issue = 64 lanes x 16 B = one 1 KB row.
    auto stage = [&](int p, int buf) {
        #pragma unroll
        for (int i = 0; i < 4; i++) {
            int r = wave * 4 + i;
            const float* src = x + (size_t)(row0 + r) * C_ + p * 256 + lane * 4;
            __builtin_amdgcn_global_load_lds(
                (const __attribute__((address_space(1))) unsigned int*)src,
                (__attribute__((address_space(3))) unsigned int*)&xraw[buf][r][0],
                16, 0, 0);
        }
    };

    f32x4 acc[3];
    #pragma unroll
    for (int i = 0; i < 3; i++) acc[i] = (f32x4){0.f, 0.f, 0.f, 0.f};

    stage(0, 0);
    stage(1, 1);
    const unsigned short* wb = Wp + (size_t)(n0 + col) * 32 + quad * 8;
    bf16x8 bcur0 = *(const bf16x8*)(wb);
    bf16x8 bcur1 = *(const bf16x8*)(wb + 16 * 32);
    bf16x8 bcur2 = *(const bf16x8*)(wb + 32 * 32);
    __syncthreads();

    for (int p = 0; p < 4; ++p) {
        if (p + 2 < 4) stage(p + 2, (p + 2) % 3);
        const char* abase = &xraw[p % 3][col][quad * 32];
        #pragma unroll
        for (int kt = 0; kt < 8; ++kt) {
            const int ktg = p * 8 + kt;
            bf16x8 bn0, bn1, bn2;
            if (ktg + 1 < 32) {
                const unsigned short* wn = wb + (size_t)(ktg + 1) * 192 * 32;
                bn0 = *(const bf16x8*)(wn);
                bn1 = *(const bf16x8*)(wn + 16 * 32);
                bn2 = *(const bf16x8*)(wn + 32 * 32);
            }
            float4 u0 = *(const float4*)(abase + kt * 128);
            float4 u1 = *(const float4*)(abase + kt * 128 + 16);
            bf16x8 a = cvt8(u0, u1);
            acc[0] = __builtin_amdgcn_mfma_f32_16x16x32_bf16(a, bcur0, acc[0], 0, 0, 0);
            acc[1] = __builtin_amdgcn_mfma_f32_16x16x32_bf16(a, bcur1, acc[1], 0, 0, 0);
            acc[2] = __builtin_amdgcn_mfma_f32_16x16x32_bf16(a, bcur2, acc[2], 0, 0, 0);
            bcur0 = bn0; bcur1 = bn1; bcur2 = bn2;
        }
        __syncthreads();
    }

    // epilogue: C/D layout col=lane&15, row=quad*4+reg; nt tile -> q/k/v by col
    #pragma unroll
    for (int nt = 0; nt < 3; nt++) {
        f32x4 s = acc[nt];
        int c = n0 + nt * 16;
        int g = c >> 6;               // 0=q, 1=k, 2=v (tiles never straddle)
        if (g < 2) {
            unsigned short* dst = (g == 0) ? q : k;
            int cc = (c & 63) + col;
            int grow = row0 + quad * 4;
            #pragma unroll
            for (int r = 0; r < 4; r++)
                dst[(size_t)(grow + r) * 64 + cc] = f2bf_u(s[r]);
        } else {
            int hh = (c - 128) + col;
            int bi = row0 >> 11, trow = (row0 & 2047) + quad * 4;
            ushort4 pk;
            pk.x = f2bf_u(s[0]); pk.y = f2bf_u(s[1]);
            pk.z = f2bf_u(s[2]); pk.w = f2bf_u(s[3]);
            *(ushort4*)(vT + ((size_t)bi * 64 + hh) * T_ + trow) = pk;
        }
    }
}

// ---- causal attention, bounded-logit softmax (no max), 8-way key split ----
// R7: explicit SW pipeline — K/V frags for it+1 live in registers while it
// computes (R6's VGPR=44 proved loads were serialized; (512,4) allows 128).
__global__ __launch_bounds__(512, 4) void attn_kernel(
        const unsigned short* __restrict__ q, const unsigned short* __restrict__ k,
        const unsigned short* __restrict__ vT, float* __restrict__ out) {
    __shared__ unsigned int tbuf[8][2][16 * 20];  // 20 KB  P^T staging
    __shared__ float so[8][16][68];               // 34.8 KB partial O^T (+pad)
    __shared__ float sl[8][16];                   // partial L
    const int wave = threadIdx.x >> 6;
    const int lane = threadIdx.x & 63;
    const int col  = lane & 15;   // query index within tile
    const int quad = lane >> 4;
    const int bi = blockIdx.x & 7;
    const int ti = 127 - (blockIdx.x >> 3);       // heavy tiles first
    const int t0 = ti * 16;
    const unsigned short* qb = q  + (size_t)bi * T_ * 64;
    const unsigned short* kb = k  + (size_t)bi * T_ * 64;
    const unsigned short* vb = vT + (size_t)bi * 64 * T_;

    f32x4 o[4];
    #pragma unroll
    for (int i = 0; i < 4; i++) o[i] = (f32x4){0.f, 0.f, 0.f, 0.f};
    float lacc = 0.f;
    const float cs = 0.03125f * 1.44269504088896f;   // C^-0.5 * log2(e)
    const int qrow = t0 + col;

    const int nit = (t0 + 47) >> 5;   // 32-key tiles for this q-tile
    const int ci  = (nit + 7) >> 3;
    const int it0 = wave * ci;
    const int it1 = min(it0 + ci, nit);

    if (it0 < it1) {
        bf16x8 qf0 = *(const bf16x8*)(qb + (size_t)(t0 + col) * 64 + quad * 8);
        bf16x8 qf1 = *(const bf16x8*)(qb + (size_t)(t0 + col) * 64 + 32 + quad * 8);

        // prologue loads for it0
        int s0 = it0 * 32;
        bf16x8 kc0 = *(const bf16x8*)(kb + (size_t)(s0 + col) * 64 + quad * 8);
        bf16x8 kc1 = *(const bf16x8*)(kb + (size_t)(s0 + col) * 64 + 32 + quad * 8);
        bf16x8 kc2 = *(const bf16x8*)(kb + (size_t)(s0 + 16 + col) * 64 + quad * 8);
        bf16x8 kc3 = *(const bf16x8*)(kb + (size_t)(s0 + 16 + col) * 64 + 32 + quad * 8);
        bf16x8 vc[4];
        #pragma unroll
        for (int ht = 0; ht < 4; ht++)
            vc[ht] = *(const bf16x8*)(vb + (size_t)(ht * 16 + col) * T_ + s0 + quad * 8);

        for (int it = it0; it < it1; ++it) {
            s0 = it * 32;
            // prefetch it+1 (clamped) — issued before any use of current frags
            const int sn = min(it + 1, it1 - 1) * 32;
            bf16x8 kn0 = *(const bf16x8*)(kb + (size_t)(sn + col) * 64 + quad * 8);
            bf16x8 kn1 = *(const bf16x8*)(kb + (size_t)(sn + col) * 64 + 32 + quad * 8);
            bf16x8 kn2 = *(const bf16x8*)(kb + (size_t)(sn + 16 + col) * 64 + quad * 8);
            bf16x8 kn3 = *(const bf16x8*)(kb + (size_t)(sn + 16 + col) * 64 + 32 + quad * 8);
            bf16x8 vn[4];
            #pragma unroll
            for (int ht = 0; ht < 4; ht++)
                vn[ht] = *(const bf16x8*)(vb + (size_t)(ht * 16 + col) * T_ + sn + quad * 8);

            f32x4 sa = (f32x4){0.f, 0.f, 0.f, 0.f};
            f32x4 sb = (f32x4){0.f, 0.f, 0.f, 0.f};
            sa = __builtin_amdgcn_mfma_f32_16x16x32_bf16(kc0, qf0, sa, 0, 0, 0);
            sa = __builtin_amdgcn_mfma_f32_16x16x32_bf16(kc1, qf1, sa, 0, 0, 0);
            sb = __builtin_amdgcn_mfma_f32_16x16x32_bf16(kc2, qf0, sb, 0, 0, 0);
            sb = __builtin_amdgcn_mfma_f32_16x16x32_bf16(kc3, qf1, sb, 0, 0, 0);

            float pa[4], pb[4];
            #pragma unroll
            for (int r = 0; r < 4; r++) {
                int ka = s0 + quad * 4 + r;
                pa[r] = (ka      <= qrow) ? exp2f(sa[r] * cs) : 0.f;
                pb[r] = (ka + 16 <= qrow) ? exp2f(sb[r] * cs) : 0.f;
                lacc += pa[r] + pb[r];
            }
            unsigned int* tb = &tbuf[wave][it & 1][0];
            *(uint2*)&tb[col * 20 + 2 * quad] =
                make_uint2(pack2(pa[0], pa[1]), pack2(pa[2], pa[3]));
            *(uint2*)&tb[col * 20 + 8 + 2 * quad] =
                make_uint2(pack2(pb[0], pb[1]), pack2(pb[2], pb[3]));
            bf16x8 pf = *(const bf16x8*)&tb[col * 20 + 4 * quad];
            #pragma unroll
            for (int ht = 0; ht < 4; ht++)
                o[ht] = __builtin_amdgcn_mfma_f32_16x16x32_bf16(vc[ht], pf, o[ht], 0, 0, 0);

            kc0 = kn0; kc1 = kn1; kc2 = kn2; kc3 = kn3;
            #pragma unroll
            for (int ht = 0; ht < 4; ht++) vc[ht] = vn[ht];
        }
    }

    // per-query L: reduce across quads (keys were split over quads)
    lacc += __shfl_xor(lacc, 16);
    lacc += __shfl_xor(lacc, 32);
    if (quad == 0) sl[wave][col] = lacc;
    #pragma unroll
    for (int ht = 0; ht < 4; ht++)
        *(f32x4*)&so[wave][col][ht * 16 + quad * 4] = o[ht];
    __syncthreads();

    // plain-sum combine of 8 partials
    for (int e = threadIdx.x; e < 1024; e += 512) {
        int qq = e >> 6, h = e & 63;
        float L = 0.f, val = 0.f;
        #pragma unroll
        for (int w = 0; w < 8; w++) { L += sl[w][qq]; val += so[w][qq][h]; }
        out[((size_t)bi * T_ + t0 + qq) * 64 + h] = val / L;
    }
}

extern "C" void kernel_launch(void* const* d_in, const int* in_sizes, int n_in,
                              void* d_out, int out_size, void* d_ws, size_t ws_size,
                              hipStream_t stream) {
    const float* x  = (const float*)d_in[0];
    const float* Wq = (const float*)d_in[1];
    const float* Wk = (const float*)d_in[2];
    const float* Wv = (const float*)d_in[3];
    float* out = (float*)d_out;

    unsigned short* Wp  = (unsigned short*)d_ws;
    unsigned short* qws = (unsigned short*)((char*)d_ws + 0x60000);
    unsigned short* kws = (unsigned short*)((char*)d_ws + 0x60000 + 0x200000);
    unsigned short* vws = (unsigned short*)((char*)d_ws + 0x60000 + 0x400000);

    prep_w_kernel<<<(C_ * 192 + 255) / 256, 256, 0, stream>>>(Wq, Wk, Wv, Wp);
    proj_kernel<<<(B_ * T_) / 16, 256, 0, stream>>>(x, Wp, qws, kws, vws);
    attn_kernel<<<(B_ * T_) / 16, 512, 0, stream>>>(qws, kws, vws, out);
}

// Round 8
// 149.892 us; speedup vs baseline: 1.1041x; 1.1041x over previous
//
#include <hip/hip_runtime.h>
#include <hip/hip_bf16.h>
#include <math.h>

#define B_ 8
#define T_ 2048
#define C_ 1024
#define H_ 64

typedef __attribute__((ext_vector_type(8))) __bf16 bf16x8;
typedef __attribute__((ext_vector_type(4))) float f32x4;

static __device__ inline unsigned short f2bf_u(float f) {
    __bf16 b = (__bf16)f;
    return __builtin_bit_cast(unsigned short, b);
}
static __device__ inline unsigned int pack2(float lo, float hi) {
    return (unsigned int)f2bf_u(lo) | ((unsigned int)f2bf_u(hi) << 16);
}
static __device__ inline bf16x8 cvt8(float4 a, float4 b) {
    bf16x8 w;
    w[0] = (__bf16)a.x; w[1] = (__bf16)a.y; w[2] = (__bf16)a.z; w[3] = (__bf16)a.w;
    w[4] = (__bf16)b.x; w[5] = (__bf16)b.y; w[6] = (__bf16)b.z; w[7] = (__bf16)b.w;
    return w;
}

// ---- pack Wq|Wk|Wv fp32 [1024][64] -> Wp bf16 [kt][n][32], n in [0,192) ----
__global__ void prep_w_kernel(const float* __restrict__ Wq,
                              const float* __restrict__ Wk,
                              const float* __restrict__ Wv,
                              unsigned short* __restrict__ Wp) {
    int idx = blockIdx.x * 256 + threadIdx.x;
    if (idx >= C_ * 192) return;
    int k = idx / 192;
    int n = idx % 192;
    const float* W = (n < 64) ? Wq : (n < 128) ? Wk : Wv;
    float val = W[k * 64 + (n & 63)];
    Wp[((size_t)(k >> 5) * 192 + n) * 32 + (k & 31)] = f2bf_u(val);
}

// ---- proj v6: block = 32 rows x 192 cols, 4 waves x 48 cols.
// R8 single-variable change vs R6: 32 rows/wave (2 m-frags) -> B-traffic
// halves (393->197 MB L2) and each B-frag feeds 2 MFMAs. Total B-bytes =
// #waves x 96 KB is the structural floor term; rows/wave is the only lever.
// Staging: R6's proven register-phase scheme, 8 phases x 4 kt.
#define XSTR 136   // short stride per row (128 + 8 pad)
__global__ __launch_bounds__(256, 2) void proj_kernel(
        const float* __restrict__ x, const unsigned short* __restrict__ Wp,
        unsigned short* __restrict__ q, unsigned short* __restrict__ k,
        unsigned short* __restrict__ vT) {
    __shared__ unsigned short xb[2][32][XSTR];   // 17.4 KB
    const int wave = threadIdx.x >> 6;
    const int lane = threadIdx.x & 63;
    const int col  = lane & 15;
    const int quad = lane >> 4;
    const int row0 = blockIdx.x * 32;
    const int n0   = wave * 48;

    // staging geometry: thread -> (row 0..31, 16-float chunk 0..7); 64B/thread
    const int srow = threadIdx.x >> 3;
    const int sf   = (threadIdx.x & 7) * 16;
    const float* sb = x + (size_t)(row0 + srow) * C_ + sf;

    f32x4 acc[6];   // [mt*3 + nt]
    #pragma unroll
    for (int i = 0; i < 6; i++) acc[i] = (f32x4){0.f, 0.f, 0.f, 0.f};

    // prologue: phase 0 -> LDS buf0; phase 1 loads held in regs
    {
        float4 t0 = *(const float4*)(sb + 0),  t1 = *(const float4*)(sb + 4);
        float4 t2 = *(const float4*)(sb + 8),  t3 = *(const float4*)(sb + 12);
        *(bf16x8*)&xb[0][srow][sf]     = cvt8(t0, t1);
        *(bf16x8*)&xb[0][srow][sf + 8] = cvt8(t2, t3);
    }
    float4 l0 = *(const float4*)(sb + 128), l1 = *(const float4*)(sb + 132);
    float4 l2 = *(const float4*)(sb + 136), l3 = *(const float4*)(sb + 140);

    const unsigned short* wb = Wp + (size_t)(n0 + col) * 32 + quad * 8;
    bf16x8 bcur0 = *(const bf16x8*)(wb);
    bf16x8 bcur1 = *(const bf16x8*)(wb + 16 * 32);
    bf16x8 bcur2 = *(const bf16x8*)(wb + 32 * 32);
    __syncthreads();

    for (int p = 0; p < 8; ++p) {
        float4 f0, f1, f2, f3;
        if (p + 2 < 8) {
            const float* s2 = sb + (p + 2) * 128;
            f0 = *(const float4*)(s2 + 0);  f1 = *(const float4*)(s2 + 4);
            f2 = *(const float4*)(s2 + 8);  f3 = *(const float4*)(s2 + 12);
        }
        #pragma unroll
        for (int ktl = 0; ktl < 4; ++ktl) {
            const int ktg = p * 4 + ktl;
            bf16x8 bn0, bn1, bn2;
            if (ktg + 1 < 32) {
                const unsigned short* wn = wb + (size_t)(ktg + 1) * 192 * 32;
                bn0 = *(const bf16x8*)(wn);
                bn1 = *(const bf16x8*)(wn + 16 * 32);
                bn2 = *(const bf16x8*)(wn + 32 * 32);
            }
            bf16x8 a0 = *(const bf16x8*)&xb[p & 1][col][ktl * 32 + quad * 8];
            bf16x8 a1 = *(const bf16x8*)&xb[p & 1][col + 16][ktl * 32 + quad * 8];
            acc[0] = __builtin_amdgcn_mfma_f32_16x16x32_bf16(a0, bcur0, acc[0], 0, 0, 0);
            acc[1] = __builtin_amdgcn_mfma_f32_16x16x32_bf16(a0, bcur1, acc[1], 0, 0, 0);
            acc[2] = __builtin_amdgcn_mfma_f32_16x16x32_bf16(a0, bcur2, acc[2], 0, 0, 0);
            acc[3] = __builtin_amdgcn_mfma_f32_16x16x32_bf16(a1, bcur0, acc[3], 0, 0, 0);
            acc[4] = __builtin_amdgcn_mfma_f32_16x16x32_bf16(a1, bcur1, acc[4], 0, 0, 0);
            acc[5] = __builtin_amdgcn_mfma_f32_16x16x32_bf16(a1, bcur2, acc[5], 0, 0, 0);
            bcur0 = bn0; bcur1 = bn1; bcur2 = bn2;
        }
        if (p + 1 < 8) {
            unsigned short* d = &xb[(p + 1) & 1][srow][sf];
            *(bf16x8*)(d)     = cvt8(l0, l1);
            *(bf16x8*)(d + 8) = cvt8(l2, l3);
            l0 = f0; l1 = f1; l2 = f2; l3 = f3;
        }
        __syncthreads();
    }

    // epilogue: C/D layout col=lane&15, row=quad*4+reg
    #pragma unroll
    for (int mt = 0; mt < 2; mt++) {
        #pragma unroll
        for (int nt = 0; nt < 3; nt++) {
            f32x4 s = acc[mt * 3 + nt];
            int c = n0 + nt * 16;
            int g = c >> 6;               // 0=q, 1=k, 2=v (tiles never straddle)
            if (g < 2) {
                unsigned short* dst = (g == 0) ? q : k;
                int cc = (c & 63) + col;
                int grow = row0 + mt * 16 + quad * 4;
                #pragma unroll
                for (int r = 0; r < 4; r++)
                    dst[(size_t)(grow + r) * 64 + cc] = f2bf_u(s[r]);
            } else {
                int hh = (c - 128) + col;
                int row = row0 + mt * 16;
                int bi = row >> 11, trow = (row & 2047) + quad * 4;
                ushort4 pk;
                pk.x = f2bf_u(s[0]); pk.y = f2bf_u(s[1]);
                pk.z = f2bf_u(s[2]); pk.w = f2bf_u(s[3]);
                *(ushort4*)(vT + ((size_t)bi * 64 + hh) * T_ + trow) = pk;
            }
        }
    }
}

// ---- causal attention (R6 version, best known ~41 us): no online softmax
// (bounded logits), 8-way key split, plain-sum combine ----
__global__ __launch_bounds__(512, 2) void attn_kernel(
        const unsigned short* __restrict__ q, const unsigned short* __restrict__ k,
        const unsigned short* __restrict__ vT, float* __restrict__ out) {
    __shared__ unsigned int tbuf[8][2][16 * 20];  // 20 KB  P^T staging
    __shared__ float so[8][16][68];               // 34.8 KB partial O^T (+pad)
    __shared__ float sl[8][16];                   // partial L
    const int wave = threadIdx.x >> 6;
    const int lane = threadIdx.x & 63;
    const int col  = lane & 15;   // query index within tile
    const int quad = lane >> 4;
    const int bi = blockIdx.x & 7;
    const int ti = 127 - (blockIdx.x >> 3);       // heavy tiles first
    const int t0 = ti * 16;
    const unsigned short* qb = q  + (size_t)bi * T_ * 64;
    const unsigned short* kb = k  + (size_t)bi * T_ * 64;
    const unsigned short* vb = vT + (size_t)bi * 64 * T_;

    bf16x8 qf0 = *(const bf16x8*)(qb + (size_t)(t0 + col) * 64 + quad * 8);
    bf16x8 qf1 = *(const bf16x8*)(qb + (size_t)(t0 + col) * 64 + 32 + quad * 8);

    f32x4 o[4];
    #pragma unroll
    for (int i = 0; i < 4; i++) o[i] = (f32x4){0.f, 0.f, 0.f, 0.f};
    float lacc = 0.f;
    const float cs = 0.03125f * 1.44269504088896f;   // C^-0.5 * log2(e)
    const int qrow = t0 + col;

    const int nit = (t0 + 47) >> 5;   // 32-key tiles this block needs
    const int ci  = (nit + 7) >> 3;
    const int it0 = wave * ci;
    const int it1 = min(it0 + ci, nit);

    for (int it = it0; it < it1; ++it) {
        const int s0 = it * 32;
        bf16x8 kf00 = *(const bf16x8*)(kb + (size_t)(s0 + col) * 64 + quad * 8);
        bf16x8 kf01 = *(const bf16x8*)(kb + (size_t)(s0 + col) * 64 + 32 + quad * 8);
        bf16x8 kf10 = *(const bf16x8*)(kb + (size_t)(s0 + 16 + col) * 64 + quad * 8);
        bf16x8 kf11 = *(const bf16x8*)(kb + (size_t)(s0 + 16 + col) * 64 + 32 + quad * 8);
        f32x4 sa = (f32x4){0.f, 0.f, 0.f, 0.f};
        f32x4 sb2 = (f32x4){0.f, 0.f, 0.f, 0.f};
        sa  = __builtin_amdgcn_mfma_f32_16x16x32_bf16(kf00, qf0, sa, 0, 0, 0);
        sa  = __builtin_amdgcn_mfma_f32_16x16x32_bf16(kf01, qf1, sa, 0, 0, 0);
        sb2 = __builtin_amdgcn_mfma_f32_16x16x32_bf16(kf10, qf0, sb2, 0, 0, 0);
        sb2 = __builtin_amdgcn_mfma_f32_16x16x32_bf16(kf11, qf1, sb2, 0, 0, 0);

        float pa[4], pb[4];
        #pragma unroll
        for (int r = 0; r < 4; r++) {
            int ka = s0 + quad * 4 + r;
            pa[r] = (ka      <= qrow) ? exp2f(sa[r]  * cs) : 0.f;
            pb[r] = (ka + 16 <= qrow) ? exp2f(sb2[r] * cs) : 0.f;
            lacc += pa[r] + pb[r];
        }
        unsigned int* tb = &tbuf[wave][it & 1][0];
        *(uint2*)&tb[col * 20 + 2 * quad] =
            make_uint2(pack2(pa[0], pa[1]), pack2(pa[2], pa[3]));
        *(uint2*)&tb[col * 20 + 8 + 2 * quad] =
            make_uint2(pack2(pb[0], pb[1]), pack2(pb[2], pb[3]));
        bf16x8 pf = *(const bf16x8*)&tb[col * 20 + 4 * quad];
        #pragma unroll
        for (int ht = 0; ht < 4; ht++) {
            bf16x8 vf = *(const bf16x8*)(vb + (size_t)(ht * 16 + col) * T_ + s0 + quad * 8);
            o[ht] = __builtin_amdgcn_mfma_f32_16x16x32_bf16(vf, pf, o[ht], 0, 0, 0);
        }
    }

    // per-query L: reduce across quads (keys were split over quads)
    lacc += __shfl_xor(lacc, 16);
    lacc += __shfl_xor(lacc, 32);
    if (quad == 0) sl[wave][col] = lacc;
    #pragma unroll
    for (int ht = 0; ht < 4; ht++)
        *(f32x4*)&so[wave][col][ht * 16 + quad * 4] = o[ht];
    __syncthreads();

    // plain-sum combine of 8 partials
    for (int e = threadIdx.x; e < 1024; e += 512) {
        int qq = e >> 6, h = e & 63;
        float L = 0.f, val = 0.f;
        #pragma unroll
        for (int w = 0; w < 8; w++) { L += sl[w][qq]; val += so[w][qq][h]; }
        out[((size_t)bi * T_ + t0 + qq) * 64 + h] = val / L;
    }
}

extern "C" void kernel_launch(void* const* d_in, const int* in_sizes, int n_in,
                              void* d_out, int out_size, void* d_ws, size_t ws_size,
                              hipStream_t stream) {
    const float* x  = (const float*)d_in[0];
    const float* Wq = (const float*)d_in[1];
    const float* Wk = (const float*)d_in[2];
    const float* Wv = (const float*)d_in[3];
    float* out = (float*)d_out;

    unsigned short* Wp  = (unsigned short*)d_ws;
    unsigned short* qws = (unsigned short*)((char*)d_ws + 0x60000);
    unsigned short* kws = (unsigned short*)((char*)d_ws + 0x60000 + 0x200000);
    unsigned short* vws = (unsigned short*)((char*)d_ws + 0x60000 + 0x400000);

    prep_w_kernel<<<(C_ * 192 + 255) / 256, 256, 0, stream>>>(Wq, Wk, Wv, Wp);
    proj_kernel<<<(B_ * T_) / 32, 256, 0, stream>>>(x, Wp, qws, kws, vws);
    attn_kernel<<<(B_ * T_) / 16, 512, 0, stream>>>(qws, kws, vws, out);
}

// Round 9
// 139.776 us; speedup vs baseline: 1.1840x; 1.0724x over previous
//
#include <hip/hip_runtime.h>
#include <hip/hip_bf16.h>
#include <math.h>

#define B_ 8
#define T_ 2048
#define C_ 1024
#define H_ 64

typedef __attribute__((ext_vector_type(8))) __bf16 bf16x8;
typedef __attribute__((ext_vector_type(4))) float f32x4;

static __device__ inline unsigned short f2bf_u(float f) {
    __bf16 b = (__bf16)f;
    return __builtin_bit_cast(unsigned short, b);
}
static __device__ inline unsigned int pack2(float lo, float hi) {
    return (unsigned int)f2bf_u(lo) | ((unsigned int)f2bf_u(hi) << 16);
}
static __device__ inline bf16x8 cvt8(float4 a, float4 b) {
    bf16x8 w;
    w[0] = (__bf16)a.x; w[1] = (__bf16)a.y; w[2] = (__bf16)a.z; w[3] = (__bf16)a.w;
    w[4] = (__bf16)b.x; w[5] = (__bf16)b.y; w[6] = (__bf16)b.z; w[7] = (__bf16)b.w;
    return w;
}

// ---- pack Wq|Wk|Wv fp32 [1024][64] -> Wp bf16 [kt][n][32], n in [0,192) ----
__global__ void prep_w_kernel(const float* __restrict__ Wq,
                              const float* __restrict__ Wk,
                              const float* __restrict__ Wv,
                              unsigned short* __restrict__ Wp) {
    int idx = blockIdx.x * 256 + threadIdx.x;
    if (idx >= C_ * 192) return;
    int k = idx / 192;
    int n = idx % 192;
    const float* W = (n < 64) ? Wq : (n < 128) ? Wk : Wv;
    float val = W[k * 64 + (n & 63)];
    Wp[((size_t)(k >> 5) * 192 + n) * 32 + (k & 31)] = f2bf_u(val);
}

// ---- proj (R8, unchanged): 32 rows x 192 cols, 2 m-frags/wave, B-reuse 2 ----
#define XSTR 136
__global__ __launch_bounds__(256, 2) void proj_kernel(
        const float* __restrict__ x, const unsigned short* __restrict__ Wp,
        unsigned short* __restrict__ q, unsigned short* __restrict__ k,
        unsigned short* __restrict__ vT) {
    __shared__ unsigned short xb[2][32][XSTR];   // 17.4 KB
    const int wave = threadIdx.x >> 6;
    const int lane = threadIdx.x & 63;
    const int col  = lane & 15;
    const int quad = lane >> 4;
    const int row0 = blockIdx.x * 32;
    const int n0   = wave * 48;

    const int srow = threadIdx.x >> 3;
    const int sf   = (threadIdx.x & 7) * 16;
    const float* sb = x + (size_t)(row0 + srow) * C_ + sf;

    f32x4 acc[6];
    #pragma unroll
    for (int i = 0; i < 6; i++) acc[i] = (f32x4){0.f, 0.f, 0.f, 0.f};

    {
        float4 t0 = *(const float4*)(sb + 0),  t1 = *(const float4*)(sb + 4);
        float4 t2 = *(const float4*)(sb + 8),  t3 = *(const float4*)(sb + 12);
        *(bf16x8*)&xb[0][srow][sf]     = cvt8(t0, t1);
        *(bf16x8*)&xb[0][srow][sf + 8] = cvt8(t2, t3);
    }
    float4 l0 = *(const float4*)(sb + 128), l1 = *(const float4*)(sb + 132);
    float4 l2 = *(const float4*)(sb + 136), l3 = *(const float4*)(sb + 140);

    const unsigned short* wb = Wp + (size_t)(n0 + col) * 32 + quad * 8;
    bf16x8 bcur0 = *(const bf16x8*)(wb);
    bf16x8 bcur1 = *(const bf16x8*)(wb + 16 * 32);
    bf16x8 bcur2 = *(const bf16x8*)(wb + 32 * 32);
    __syncthreads();

    for (int p = 0; p < 8; ++p) {
        float4 f0, f1, f2, f3;
        if (p + 2 < 8) {
            const float* s2 = sb + (p + 2) * 128;
            f0 = *(const float4*)(s2 + 0);  f1 = *(const float4*)(s2 + 4);
            f2 = *(const float4*)(s2 + 8);  f3 = *(const float4*)(s2 + 12);
        }
        #pragma unroll
        for (int ktl = 0; ktl < 4; ++ktl) {
            const int ktg = p * 4 + ktl;
            bf16x8 bn0, bn1, bn2;
            if (ktg + 1 < 32) {
                const unsigned short* wn = wb + (size_t)(ktg + 1) * 192 * 32;
                bn0 = *(const bf16x8*)(wn);
                bn1 = *(const bf16x8*)(wn + 16 * 32);
                bn2 = *(const bf16x8*)(wn + 32 * 32);
            }
            bf16x8 a0 = *(const bf16x8*)&xb[p & 1][col][ktl * 32 + quad * 8];
            bf16x8 a1 = *(const bf16x8*)&xb[p & 1][col + 16][ktl * 32 + quad * 8];
            acc[0] = __builtin_amdgcn_mfma_f32_16x16x32_bf16(a0, bcur0, acc[0], 0, 0, 0);
            acc[1] = __builtin_amdgcn_mfma_f32_16x16x32_bf16(a0, bcur1, acc[1], 0, 0, 0);
            acc[2] = __builtin_amdgcn_mfma_f32_16x16x32_bf16(a0, bcur2, acc[2], 0, 0, 0);
            acc[3] = __builtin_amdgcn_mfma_f32_16x16x32_bf16(a1, bcur0, acc[3], 0, 0, 0);
            acc[4] = __builtin_amdgcn_mfma_f32_16x16x32_bf16(a1, bcur1, acc[4], 0, 0, 0);
            acc[5] = __builtin_amdgcn_mfma_f32_16x16x32_bf16(a1, bcur2, acc[5], 0, 0, 0);
            bcur0 = bn0; bcur1 = bn1; bcur2 = bn2;
        }
        if (p + 1 < 8) {
            unsigned short* d = &xb[(p + 1) & 1][srow][sf];
            *(bf16x8*)(d)     = cvt8(l0, l1);
            *(bf16x8*)(d + 8) = cvt8(l2, l3);
            l0 = f0; l1 = f1; l2 = f2; l3 = f3;
        }
        __syncthreads();
    }

    #pragma unroll
    for (int mt = 0; mt < 2; mt++) {
        #pragma unroll
        for (int nt = 0; nt < 3; nt++) {
            f32x4 s = acc[mt * 3 + nt];
            int c = n0 + nt * 16;
            int g = c >> 6;
            if (g < 2) {
                unsigned short* dst = (g == 0) ? q : k;
                int cc = (c & 63) + col;
                int grow = row0 + mt * 16 + quad * 4;
                #pragma unroll
                for (int r = 0; r < 4; r++)
                    dst[(size_t)(grow + r) * 64 + cc] = f2bf_u(s[r]);
            } else {
                int hh = (c - 128) + col;
                int row = row0 + mt * 16;
                int bi = row >> 11, trow = (row & 2047) + quad * 4;
                ushort4 pk;
                pk.x = f2bf_u(s[0]); pk.y = f2bf_u(s[1]);
                pk.z = f2bf_u(s[2]); pk.w = f2bf_u(s[3]);
                *(ushort4*)(vT + ((size_t)bi * 64 + hh) * T_ + trow) = pk;
            }
        }
    }
}

// ---- attn v5: 32 queries/block (2 q-tiles PER WAVE), 8-way key split.
// R9 lever (same as proj's R8 win): each 8-load K/V iteration now feeds 16
// MFMAs instead of 8; total wave-iterations halve (34k -> 17.5k). Combine is
// hierarchical (waves 4-7 write, waves 0-3 RMW, joint reduce) to fit 2 blk/CU.
__global__ __launch_bounds__(512, 4) void attn_kernel(
        const unsigned short* __restrict__ q, const unsigned short* __restrict__ k,
        const unsigned short* __restrict__ vT, float* __restrict__ out) {
    __shared__ unsigned int tbuf[8][640];   // 20 KB: per-wave P^T, 2 tiles x 16x20
    __shared__ float so[4][32][68];         // 34.8 KB partial O (+pad)
    __shared__ float sl[4][32];             // partial L
    const int wave = threadIdx.x >> 6;
    const int lane = threadIdx.x & 63;
    const int col  = lane & 15;
    const int quad = lane >> 4;
    const int bi = blockIdx.x & 7;
    const int m  = 63 - (blockIdx.x >> 3);   // heavy tiles first
    const int t0 = m * 32;
    const unsigned short* qb = q  + (size_t)bi * T_ * 64;
    const unsigned short* kb = k  + (size_t)bi * T_ * 64;
    const unsigned short* vb = vT + (size_t)bi * 64 * T_;

    f32x4 o[2][4];
    #pragma unroll
    for (int t = 0; t < 2; t++)
        #pragma unroll
        for (int i = 0; i < 4; i++) o[t][i] = (f32x4){0.f, 0.f, 0.f, 0.f};
    float laccA = 0.f, laccB = 0.f;
    const float cs = 0.03125f * 1.44269504088896f;   // C^-0.5 * log2(e)
    const int qrowA = t0 + col;
    const int qrowB = t0 + 16 + col;

    const int nit = m + 2;                 // 32-key tiles covering keys < t0+32
    const int ci  = (nit + 7) >> 3;
    const int it0 = wave * ci;
    const int it1 = min(it0 + ci, nit);

    if (it0 < it1) {
        bf16x8 qA0 = *(const bf16x8*)(qb + (size_t)(t0 + col) * 64 + quad * 8);
        bf16x8 qA1 = *(const bf16x8*)(qb + (size_t)(t0 + col) * 64 + 32 + quad * 8);
        bf16x8 qB0 = *(const bf16x8*)(qb + (size_t)(t0 + 16 + col) * 64 + quad * 8);
        bf16x8 qB1 = *(const bf16x8*)(qb + (size_t)(t0 + 16 + col) * 64 + 32 + quad * 8);
        unsigned int* tb = &tbuf[wave][0];

        for (int it = it0; it < it1; ++it) {
            const int s0 = it * 32;
            bf16x8 kf00 = *(const bf16x8*)(kb + (size_t)(s0 + col) * 64 + quad * 8);
            bf16x8 kf01 = *(const bf16x8*)(kb + (size_t)(s0 + col) * 64 + 32 + quad * 8);
            bf16x8 kf10 = *(const bf16x8*)(kb + (size_t)(s0 + 16 + col) * 64 + quad * 8);
            bf16x8 kf11 = *(const bf16x8*)(kb + (size_t)(s0 + 16 + col) * 64 + 32 + quad * 8);
            bf16x8 vf[4];
            #pragma unroll
            for (int ht = 0; ht < 4; ht++)
                vf[ht] = *(const bf16x8*)(vb + (size_t)(ht * 16 + col) * T_ + s0 + quad * 8);

            f32x4 saA = (f32x4){0.f, 0.f, 0.f, 0.f};
            f32x4 sbA = (f32x4){0.f, 0.f, 0.f, 0.f};
            f32x4 saB = (f32x4){0.f, 0.f, 0.f, 0.f};
            f32x4 sbB = (f32x4){0.f, 0.f, 0.f, 0.f};
            saA = __builtin_amdgcn_mfma_f32_16x16x32_bf16(kf00, qA0, saA, 0, 0, 0);
            saA = __builtin_amdgcn_mfma_f32_16x16x32_bf16(kf01, qA1, saA, 0, 0, 0);
            sbA = __builtin_amdgcn_mfma_f32_16x16x32_bf16(kf10, qA0, sbA, 0, 0, 0);
            sbA = __builtin_amdgcn_mfma_f32_16x16x32_bf16(kf11, qA1, sbA, 0, 0, 0);
            saB = __builtin_amdgcn_mfma_f32_16x16x32_bf16(kf00, qB0, saB, 0, 0, 0);
            saB = __builtin_amdgcn_mfma_f32_16x16x32_bf16(kf01, qB1, saB, 0, 0, 0);
            sbB = __builtin_amdgcn_mfma_f32_16x16x32_bf16(kf10, qB0, sbB, 0, 0, 0);
            sbB = __builtin_amdgcn_mfma_f32_16x16x32_bf16(kf11, qB1, sbB, 0, 0, 0);

            float pa[4], pb[4], pc[4], pd[4];
            #pragma unroll
            for (int r = 0; r < 4; r++) {
                int ka = s0 + quad * 4 + r;
                pa[r] = (ka      <= qrowA) ? exp2f(saA[r] * cs) : 0.f;
                pb[r] = (ka + 16 <= qrowA) ? exp2f(sbA[r] * cs) : 0.f;
                pc[r] = (ka      <= qrowB) ? exp2f(saB[r] * cs) : 0.f;
                pd[r] = (ka + 16 <= qrowB) ? exp2f(sbB[r] * cs) : 0.f;
                laccA += pa[r] + pb[r];
                laccB += pc[r] + pd[r];
            }
            *(uint2*)&tb[col * 20 + 2 * quad] =
                make_uint2(pack2(pa[0], pa[1]), pack2(pa[2], pa[3]));
            *(uint2*)&tb[col * 20 + 8 + 2 * quad] =
                make_uint2(pack2(pb[0], pb[1]), pack2(pb[2], pb[3]));
            *(uint2*)&tb[320 + col * 20 + 2 * quad] =
                make_uint2(pack2(pc[0], pc[1]), pack2(pc[2], pc[3]));
            *(uint2*)&tb[320 + col * 20 + 8 + 2 * quad] =
                make_uint2(pack2(pd[0], pd[1]), pack2(pd[2], pd[3]));
            bf16x8 pfA = *(const bf16x8*)&tb[col * 20 + 4 * quad];
            bf16x8 pfB = *(const bf16x8*)&tb[320 + col * 20 + 4 * quad];
            #pragma unroll
            for (int ht = 0; ht < 4; ht++) {
                o[0][ht] = __builtin_amdgcn_mfma_f32_16x16x32_bf16(vf[ht], pfA, o[0][ht], 0, 0, 0);
                o[1][ht] = __builtin_amdgcn_mfma_f32_16x16x32_bf16(vf[ht], pfB, o[1][ht], 0, 0, 0);
            }
        }
    }

    // per-query L: reduce across quads (keys split over quads within a wave)
    laccA += __shfl_xor(laccA, 16); laccA += __shfl_xor(laccA, 32);
    laccB += __shfl_xor(laccB, 16); laccB += __shfl_xor(laccB, 32);

    // hierarchical combine: waves 4-7 write partials; waves 0-3 RMW-add theirs
    if (wave >= 4) {
        int s = wave - 4;
        #pragma unroll
        for (int t = 0; t < 2; t++)
            #pragma unroll
            for (int ht = 0; ht < 4; ht++)
                *(f32x4*)&so[s][t * 16 + col][ht * 16 + quad * 4] = o[t][ht];
        if (quad == 0) { sl[s][col] = laccA; sl[s][16 + col] = laccB; }
    }
    __syncthreads();
    if (wave < 4) {
        #pragma unroll
        for (int t = 0; t < 2; t++)
            #pragma unroll
            for (int ht = 0; ht < 4; ht++) {
                f32x4 cur = *(f32x4*)&so[wave][t * 16 + col][ht * 16 + quad * 4];
                cur += o[t][ht];
                *(f32x4*)&so[wave][t * 16 + col][ht * 16 + quad * 4] = cur;
            }
        if (quad == 0) { sl[wave][col] += laccA; sl[wave][16 + col] += laccB; }
    }
    __syncthreads();

    for (int e = threadIdx.x; e < 2048; e += 512) {
        int qq = e >> 6, h = e & 63;
        float L = sl[0][qq] + sl[1][qq] + sl[2][qq] + sl[3][qq];
        float val = so[0][qq][h] + so[1][qq][h] + so[2][qq][h] + so[3][qq][h];
        out[((size_t)bi * T_ + t0 + qq) * 64 + h] = val / L;
    }
}

extern "C" void kernel_launch(void* const* d_in, const int* in_sizes, int n_in,
                              void* d_out, int out_size, void* d_ws, size_t ws_size,
                              hipStream_t stream) {
    const float* x  = (const float*)d_in[0];
    const float* Wq = (const float*)d_in[1];
    const float* Wk = (const float*)d_in[2];
    const float* Wv = (const float*)d_in[3];
    float* out = (float*)d_out;

    unsigned short* Wp  = (unsigned short*)d_ws;
    unsigned short* qws = (unsigned short*)((char*)d_ws + 0x60000);
    unsigned short* kws = (unsigned short*)((char*)d_ws + 0x60000 + 0x200000);
    unsigned short* vws = (unsigned short*)((char*)d_ws + 0x60000 + 0x400000);

    prep_w_kernel<<<(C_ * 192 + 255) / 256, 256, 0, stream>>>(Wq, Wk, Wv, Wp);
    proj_kernel<<<(B_ * T_) / 32, 256, 0, stream>>>(x, Wp, qws, kws, vws);
    attn_kernel<<<(B_ * T_) / 32, 512, 0, stream>>>(qws, kws, vws, out);
}